// Round 2
// baseline (210.354 us; speedup 1.0000x reference)
//
#include <hip/hip_runtime.h>
#include <hip/hip_bf16.h>
#include <stdint.h>

typedef unsigned short u16;
typedef unsigned int u32;

#define N_NODES 2708
#define IN_C    2048
#define OUT_C   512
#define MP      2816   // padded node count (multiple of 128)
#define KP      2816   // padded K for gemm2 (= MP)

using floatx4 = __attribute__((ext_vector_type(4))) float;
using short8  = __attribute__((ext_vector_type(8))) short;

// ---- workspace layout ----
constexpr size_t XB_OFF = 0;
constexpr size_t XB_SZ  = (size_t)MP * IN_C * 2;      // 11,534,336
constexpr size_t WB_OFF = XB_OFF + XB_SZ;
constexpr size_t WB_SZ  = (size_t)OUT_C * IN_C * 2;   //  2,097,152
constexpr size_t HT_OFF = WB_OFF + WB_SZ;
constexpr size_t HT_SZ  = (size_t)OUT_C * MP * 2;     //  2,883,584
constexpr size_t AF_OFF = HT_OFF + HT_SZ;
constexpr size_t AF_SZ  = (size_t)MP * KP * 4;        // 31,719,424
constexpr size_t WS_NEED = AF_OFF + AF_SZ;            // 48,234,496 (~46 MB)

static __device__ __forceinline__ u16 f2bf(float f) {
  union { float f; u32 u; } v; v.f = f;
  u32 r = v.u + 0x7fffu + ((v.u >> 16) & 1u);  // RNE
  return (u16)(r >> 16);
}

// x [2708][2048] f32 -> xb [2816][2048] bf16, zero-padded rows
__global__ void k_convert_x(const float* __restrict__ x, u16* __restrict__ xb) {
  int i8  = blockIdx.x * 256 + threadIdx.x;   // one thread = 8 elems
  int row = i8 >> 8;                          // IN_C/8 = 256 chunks/row
  int col = (i8 & 255) * 8;
  union { u16 u[8]; uint4 v; } o;
  if (row < N_NODES) {
    float4 v0 = *(const float4*)&x[(size_t)row * IN_C + col];
    float4 v1 = *(const float4*)&x[(size_t)row * IN_C + col + 4];
    o.u[0]=f2bf(v0.x); o.u[1]=f2bf(v0.y); o.u[2]=f2bf(v0.z); o.u[3]=f2bf(v0.w);
    o.u[4]=f2bf(v1.x); o.u[5]=f2bf(v1.y); o.u[6]=f2bf(v1.z); o.u[7]=f2bf(v1.w);
  } else {
    o.v = make_uint4(0,0,0,0);
  }
  *(uint4*)&xb[(size_t)row * IN_C + col] = o.v;
}

// w [512][2048] f32 -> wb bf16
__global__ void k_convert_w(const float* __restrict__ w, u16* __restrict__ wb) {
  int i8  = blockIdx.x * 256 + threadIdx.x;
  int idx = i8 * 8;
  float4 v0 = *(const float4*)&w[idx];
  float4 v1 = *(const float4*)&w[idx + 4];
  union { u16 u[8]; uint4 v; } o;
  o.u[0]=f2bf(v0.x); o.u[1]=f2bf(v0.y); o.u[2]=f2bf(v0.z); o.u[3]=f2bf(v0.w);
  o.u[4]=f2bf(v1.x); o.u[5]=f2bf(v1.y); o.u[6]=f2bf(v1.z); o.u[7]=f2bf(v1.w);
  *(uint4*)&wb[idx] = o.v;
}

__global__ void k_zero(float4* __restrict__ p, int n) {
  int stride = gridDim.x * blockDim.x;
  for (int i = blockIdx.x * blockDim.x + threadIdx.x; i < n; i += stride)
    p[i] = make_float4(0.f, 0.f, 0.f, 0.f);
}

// edge counts: Af[dst][src] += 1
__global__ void k_count(const int* __restrict__ ei, float* __restrict__ Af, int E) {
  int e = blockIdx.x * 256 + threadIdx.x;
  if (e < E) {
    int src = ei[e];
    int dst = ei[E + e];
    atomicAdd(&Af[(size_t)dst * KP + src], 1.0f);
  }
}

// GEMM1: hT[n][m] = sum_k xb[m][k]*wb[n][k] + bias[n]
// tile 128(M) x 64(N) x 32(K); 4 waves in 2x2 (wave tile 64x32)
__global__ __launch_bounds__(256) void k_gemm1(
    const u16* __restrict__ A,    // xb [MP][IN_C]
    const u16* __restrict__ B,    // wb [OUT_C][IN_C]
    const float* __restrict__ bias,
    u16* __restrict__ hT)         // [OUT_C][MP]
{
  __shared__ u16 lA[128 * 32];
  __shared__ u16 lB[64 * 32];
  const int tid = threadIdx.x, lane = tid & 63, wid = tid >> 6;
  const int bm = blockIdx.y * 128, bn = blockIdx.x * 64;
  const int wr = wid >> 1, wc = wid & 1;

  const int srow = tid >> 2;            // 0..63
  const int scol = (tid & 3) * 8;       // 0,8,16,24
  const size_t gA1 = (size_t)(bm + srow) * IN_C + scol;
  const size_t gA2 = (size_t)(bm + 64 + srow) * IN_C + scol;
  const size_t gB  = (size_t)(bn + srow) * IN_C + scol;

  floatx4 acc[4][2] = {};

  for (int k0 = 0; k0 < IN_C; k0 += 32) {
    uint4 va1 = *(const uint4*)&A[gA1 + k0];
    uint4 va2 = *(const uint4*)&A[gA2 + k0];
    uint4 vb  = *(const uint4*)&B[gB + k0];
    __syncthreads();
    *(uint4*)&lA[srow * 32 + scol]        = va1;
    *(uint4*)&lA[(64 + srow) * 32 + scol] = va2;
    *(uint4*)&lB[srow * 32 + scol]        = vb;
    __syncthreads();
    short8 af[4], bf[2];
#pragma unroll
    for (int mi = 0; mi < 4; ++mi)
      af[mi] = *(const short8*)&lA[(wr * 64 + mi * 16 + (lane & 15)) * 32 + (lane >> 4) * 8];
#pragma unroll
    for (int ni = 0; ni < 2; ++ni)
      bf[ni] = *(const short8*)&lB[(wc * 32 + ni * 16 + (lane & 15)) * 32 + (lane >> 4) * 8];
#pragma unroll
    for (int mi = 0; mi < 4; ++mi)
#pragma unroll
      for (int ni = 0; ni < 2; ++ni)
        acc[mi][ni] = __builtin_amdgcn_mfma_f32_16x16x32_bf16(af[mi], bf[ni], acc[mi][ni], 0, 0, 0);
  }

  const int lr = (lane >> 4) * 4;
  const int lc = lane & 15;
#pragma unroll
  for (int ni = 0; ni < 2; ++ni) {
    const int n = bn + wc * 32 + ni * 16 + lc;
    const float bv = bias[n];
#pragma unroll
    for (int mi = 0; mi < 4; ++mi)
#pragma unroll
      for (int j = 0; j < 4; ++j) {
        const int m = bm + wr * 64 + mi * 16 + lr + j;
        hT[(size_t)n * MP + m] = f2bf(acc[mi][ni][j] + bv);
      }
  }
}

// GEMM2: out[m=dst][n] = sum_k Af[m][k] * hT[n][k]   (k = src node)
__global__ __launch_bounds__(256) void k_gemm2(
    const float* __restrict__ Af,  // [MP][KP] f32 counts
    const u16* __restrict__ Bh,    // hT [OUT_C][MP] bf16
    float* __restrict__ out)       // [N_NODES][OUT_C] f32
{
  __shared__ u16 lA[128 * 32];
  __shared__ u16 lB[64 * 32];
  const int tid = threadIdx.x, lane = tid & 63, wid = tid >> 6;
  const int bm = blockIdx.y * 128, bn = blockIdx.x * 64;
  const int wr = wid >> 1, wc = wid & 1;

  // A staging: 128x32 f32 -> bf16 ; 4 chunks of float4 per thread
  const int arow = tid >> 3;            // 0..31
  const int acol = (tid & 7) * 4;       // 0,4,...,28
  // B staging: 64x32 bf16 ; 1 chunk of 16B per thread
  const int brow = tid >> 2;
  const int bcol = (tid & 3) * 8;
  const size_t gB = (size_t)(bn + brow) * MP + bcol;

  floatx4 acc[4][2] = {};

  for (int k0 = 0; k0 < KP; k0 += 32) {
    float4 va[4];
#pragma unroll
    for (int j = 0; j < 4; ++j)
      va[j] = *(const float4*)&Af[(size_t)(bm + j * 32 + arow) * KP + k0 + acol];
    uint4 vb = *(const uint4*)&Bh[gB + k0];
    __syncthreads();
#pragma unroll
    for (int j = 0; j < 4; ++j) {
      union { u16 u[4]; uint2 v; } o;
      o.u[0] = f2bf(va[j].x); o.u[1] = f2bf(va[j].y);
      o.u[2] = f2bf(va[j].z); o.u[3] = f2bf(va[j].w);
      *(uint2*)&lA[(j * 32 + arow) * 32 + acol] = o.v;
    }
    *(uint4*)&lB[brow * 32 + bcol] = vb;
    __syncthreads();
    short8 af[4], bf[2];
#pragma unroll
    for (int mi = 0; mi < 4; ++mi)
      af[mi] = *(const short8*)&lA[(wr * 64 + mi * 16 + (lane & 15)) * 32 + (lane >> 4) * 8];
#pragma unroll
    for (int ni = 0; ni < 2; ++ni)
      bf[ni] = *(const short8*)&lB[(wc * 32 + ni * 16 + (lane & 15)) * 32 + (lane >> 4) * 8];
#pragma unroll
    for (int mi = 0; mi < 4; ++mi)
#pragma unroll
      for (int ni = 0; ni < 2; ++ni)
        acc[mi][ni] = __builtin_amdgcn_mfma_f32_16x16x32_bf16(af[mi], bf[ni], acc[mi][ni], 0, 0, 0);
  }

  const int lr = (lane >> 4) * 4;
  const int lc = lane & 15;
#pragma unroll
  for (int ni = 0; ni < 2; ++ni) {
    const int n = bn + wc * 32 + ni * 16 + lc;
#pragma unroll
    for (int mi = 0; mi < 4; ++mi)
#pragma unroll
      for (int j = 0; j < 4; ++j) {
        const int m = bm + wr * 64 + mi * 16 + lr + j;
        if (m < N_NODES) out[(size_t)m * OUT_C + n] = acc[mi][ni][j];
      }
  }
}

extern "C" void kernel_launch(void* const* d_in, const int* in_sizes, int n_in,
                              void* d_out, int out_size, void* d_ws, size_t ws_size,
                              hipStream_t stream) {
  const float* x    = (const float*)d_in[0];
  const int*   ei   = (const int*)d_in[1];
  const float* w    = (const float*)d_in[2];
  const float* bias = (const float*)d_in[3];
  float* out = (float*)d_out;

  char* ws = (char*)d_ws;
  u16*   xb = (u16*)(ws + XB_OFF);
  u16*   wb = (u16*)(ws + WB_OFF);
  u16*   hT = (u16*)(ws + HT_OFF);
  float* Af = (float*)(ws + AF_OFF);

  const int E = in_sizes[1] / 2;  // 500000

  k_convert_x<<<dim3(MP * IN_C / 8 / 256), dim3(256), 0, stream>>>(x, xb);
  k_convert_w<<<dim3(OUT_C * IN_C / 8 / 256), dim3(256), 0, stream>>>(w, wb);
  k_zero<<<dim3(2048), dim3(256), 0, stream>>>((float4*)Af, (int)(AF_SZ / 16));
  k_count<<<dim3((E + 255) / 256), dim3(256), 0, stream>>>(ei, Af, E);
  k_gemm1<<<dim3(OUT_C / 64, MP / 128), dim3(256), 0, stream>>>(xb, wb, bias, hT);
  k_gemm2<<<dim3(OUT_C / 64, MP / 128), dim3(256), 0, stream>>>(Af, hT, out);
}